// Round 15
// baseline (41.341 us; speedup 1.0000x reference)
//
#include <hip/hip_runtime.h>
#include <math.h>

#define BATCH 64
#define NUM_TRAJ 128
#define NTOT (BATCH*NUM_TRAJ)
#define NSTEPS 255

static constexpr float DT = 0.00390625f; // 2^-8

// DPP shuffle (compile-time ctrl), float. quad_perm: ctrl<256; row_ror:N =
// 0x120+N (rows of 16); row_half_mirror = 0x141 (lane^7 within 8).
template<int C>
__device__ __forceinline__ float qp(float x) {
    union { float f; int i; } u;
    u.f = x;
    u.i = __builtin_amdgcn_update_dpp(0, u.i, C, 0xF, 0xF, true);
    return u.f;
}
#define DPP_HALF_MIRROR 0x141   // lane^7 within each 8-lane half-row
#define DPP_ROR8        0x128   // lane^8 within each 16-lane row (ror:8)

// Cross-row sum within a quad (rows {1,2} for r in {0,3}; {0,3} for r in
// {1,2}) — valid for identity and mirrored quads (verified R5/R6/R11).
__device__ __forceinline__ float qsum2(float x) { return qp<65>(x) + qp<190>(x); }

// 16 lanes per trajectory, one complex element per lane (verified R11):
// lane L: hh=L>>3 (0: colA, 1: colB), l8=L&7, p=l8&3, c=l8>>2,
// r = c ? 3-p : p, col = hh ? (c?2:3) : (c?1:0).
//  - u (pair sum)            = x + ror8(x)
//  - up (partner pair's u)   = half_mirror(u)
//  - S (cross-row, own col)  = qsum2(x)
//  - trace all-16 reduce     = xor1 + xor2 + mirror7 + ror8  (REAL only — R14:
//    rho stays Hermitian, Im(rho_ii)=0 up to rounding; ui ~1e-7, contribution
//    over 255 steps ~1e-5 vs threshold 2e-2; f64 ref carries it at ~1e-16)
// 2048 waves = 2/SIMD: R11 measured 2.9-4.0 cyc/instr at 70% VALUBusy vs 5.1
// at 1 wave/SIMD — TLP hides the in-order dependent-issue stalls. R11's loss
// was the doubled complex trace pipeline, which R14's physics cut removes.
__global__ __launch_bounds__(64) void traj_kernel(
    const float* __restrict__ inputs,
    const float* __restrict__ params,
    const float* __restrict__ wvec,
    const float* __restrict__ rho0,
    int rho0_cplx,
    float* __restrict__ ws)
{
    const int tid = blockIdx.x * 64 + threadIdx.x;
    const int g   = tid >> 4;         // trajectory index
    const int L   = tid & 15;         // lane within 16-lane group
    const int hh  = L >> 3;           // 0 = colA element, 1 = colB element
    const int l8  = L & 7;
    const int p   = l8 & 3;
    const int c   = l8 >> 2;          // column pair: 0->{0,3}, 1->{1,2}
    const int r   = c ? (3 - p) : p;  // row (mirrored quads 1 and 3)
    const int col = hh ? (c ? 2 : 3) : (c ? 1 : 0);
    const int b   = g & (BATCH - 1);

    const float Omega = inputs[b] + 1e-8f;
    const float a     = 0.5f * Omega;
    const float eps   = params[1];
    const float Gamma = params[2];
    const float eta   = params[3];
    const float sqge  = sqrtf(fmaxf(Gamma * eta, 0.0f));
    const float gdt   = Gamma * DT;

    // per-lane constants (identical derivation to R11)
    const float s1r = (r   < 2) ? 1.0f : -1.0f;   // C1 diag
    const float s2r = (r   & 1) ? -1.0f : 1.0f;   // C2 diag
    const float s1c = (col < 2) ? 1.0f : -1.0f;
    const float s2c = (col & 1) ? -1.0f : 1.0f;
    const float hr  = (r   == 0) ? eps : ((r   == 3) ? -eps : 0.0f);
    const float hc  = (col == 0) ? eps : ((col == 3) ? -eps : 0.0f);
    const float coef = hr - hc;                   // comm diagonal coefficient
    const float dm  = gdt * (s1r * s1c + s2r * s2c - 2.0f);
    const float S1  = s1r * sqge;                 // pown = S1*dwA + S2*dwB
    const float S2  = s2r * sqge;
    const float PA  = s1c * sqge;                 // pcol = PA*dwA + PB*dwB
    const float PB  = s2c * sqge;
    const float f   = (r == col) ? 1.0f : 0.0f;   // diag ownership
    const float FA  = 2.0f * f * S1;              // trace weight t = FA*dwA+FB*dwB
    const float FB  = 2.0f * f * S2;

    float x_re, x_im;
    {
        const int idx = r * 4 + col;
        if (rho0_cplx) { x_re = rho0[2 * idx]; x_im = rho0[2 * idx + 1]; }
        else           { x_re = rho0[idx];     x_im = 0.0f; }
    }

    const float2* wp2 = reinterpret_cast<const float2*>(wvec) + (size_t)g * NSTEPS;

    auto step = [&](float dwA, float dwB) {
        // pair sum (own (r,cpair)) + partner exchange
        const float u_re = x_re + qp<DPP_ROR8>(x_re);
        const float u_im = x_im + qp<DPP_ROR8>(x_im);
        const float up_re = qp<DPP_HALF_MIRROR>(u_re);
        const float up_im = qp<DPP_HALF_MIRROR>(u_im);

        // cross-row sum in own column (within quad)
        const float S_re = qsum2(x_re);
        const float S_im = qsum2(x_im);

        // comm element: (h_r - h_col)*x + a*(S - up)
        const float cm_re = fmaf(coef, x_re, a * (S_re - up_re));
        const float cm_im = fmaf(coef, x_im, a * (S_im - up_im));

        // REAL trace: u_tr = sum_diag 2*p_r*rho_rr ; 16-lane all-reduce (4 stages)
        const float t = fmaf(FA, dwA, FB * dwB);
        float z = t * x_re;
        z += qp<177>(z);              // quad xor1
        z += qp<78>(z);               // quad xor2
        z += qp<DPP_HALF_MIRROR>(z);  // lane^7
        z += qp<DPP_ROR8>(z);         // lane^8
        const float ur = z;

        const float pown = fmaf(S1, dwA, S2 * dwB);
        const float pcol = fmaf(PA, dwA, PB * dwB);
        const float W = (pown - ur) + (pcol + dm);

        // n = x + DT*(cm_im,-cm_re) + W*x   (ui term dropped — Hermiticity)
        float n_re = fmaf(DT, cm_im, x_re);
        n_re = fmaf(W, x_re, n_re);
        float n_im = fmaf(-DT, cm_re, x_im);
        n_im = fmaf(W, x_im, n_im);
        x_re = n_re; x_im = n_im;
    };

    // 31 chunks of 8 steps + tail of 7; group-identical direct loads,
    // double-buffered one chunk ahead.
    float2 cw[8], nw[8];
#pragma unroll
    for (int s = 0; s < 8; ++s) cw[s] = wp2[s];
#pragma unroll 1
    for (int T = 0; T < 31; ++T) {
        if (T < 30) {
#pragma unroll
            for (int s = 0; s < 8; ++s) nw[s] = wp2[8 * (T + 1) + s];
        } else {
#pragma unroll
            for (int s = 0; s < 7; ++s) nw[s] = wp2[248 + s];
            nw[7] = make_float2(0.f, 0.f);
        }
#pragma unroll
        for (int s = 0; s < 8; ++s) step(cw[s].x, cw[s].y);
#pragma unroll
        for (int s = 0; s < 8; ++s) cw[s] = nw[s];
    }
#pragma unroll
    for (int s = 0; s < 7; ++s) step(cw[s].x, cw[s].y);

    // ws per trajectory: lane L stores float2 (re, im) at slot L (R11 layout)
    reinterpret_cast<float2*>(ws + (size_t)g * 32)[L] = make_float2(x_re, x_im);
}

__device__ inline void fill_proj(int p, float s, float pr[2][2], float pim[2][2])
{
    pr[0][0] = 0.5f; pr[0][1] = 0.f; pr[1][0] = 0.f; pr[1][1] = 0.5f;
    pim[0][0] = 0.f; pim[0][1] = 0.f; pim[1][0] = 0.f; pim[1][1] = 0.f;
    const float h = 0.5f * s;
    if (p == 0)      { pr[0][1] += h;  pr[1][0] += h; }   // sigma_x
    else if (p == 1) { pim[0][1] -= h; pim[1][0] += h; }  // sigma_y
    else             { pr[0][0] += h;  pr[1][1] -= h; }   // sigma_z
}

__device__ inline void fill_id(float pr[2][2], float pim[2][2])
{
    pr[0][0] = 1.f; pr[0][1] = 0.f; pr[1][0] = 0.f; pr[1][1] = 1.f;
    pim[0][0] = 0.f; pim[0][1] = 0.f; pim[1][0] = 0.f; pim[1][1] = 0.f;
}

// One block per batch element (R11 layout): ws element map for (i,j):
// cc=(j==1||j==2), hh=(j==2||j==3), p = cc ? 3-i : i,
// lane = hh*8 + cc*4 + p, float index = lane*2 + plane.
__global__ __launch_bounds__(256) void reduce_meas_kernel(
    const float* __restrict__ ws,
    const float* __restrict__ inputs,
    float* __restrict__ out,
    int out_size)
{
    const int b = blockIdx.x;
    const int tid = threadIdx.x;
    __shared__ float part[8][32];
    __shared__ float sr[16], si[16];

    {   // 256 threads: element e (32) x k-eighth h (8)
        const int e = tid & 31;
        const int h = tid >> 5;
        const int plane = e >> 4;       // 0 = re, 1 = im
        const int el = e & 15;
        const int i = el >> 2, j = el & 3;
        const int cc = (j == 1 || j == 2) ? 1 : 0;
        const int hh = (j == 2 || j == 3) ? 1 : 0;
        const int p  = cc ? (3 - i) : i;
        const int fidx = (hh * 8 + cc * 4 + p) * 2 + plane;
        float s = 0.f;
#pragma unroll 4
        for (int k = h * 16; k < h * 16 + 16; k++)
            s += ws[((size_t)(k * BATCH + b)) * 32 + fidx];
        part[h][e] = s;
    }
    __syncthreads();
    if (tid < 32) {
        float s = 0.f;
#pragma unroll
        for (int h = 0; h < 8; h++) s += part[h][tid];
        s *= (1.0f / NUM_TRAJ);
        if (tid < 16) sr[tid] = s; else si[tid - 16] = s;
    }
    __syncthreads();

    if (tid < 42) {
        float par[2][2], pai[2][2], pbr[2][2], pbi[2][2];
        const int m = tid;
        if (m < 36) {
            const int ia = m / 12, rem = m - ia * 12;
            const int ib = rem / 4, r2 = rem - ib * 4;
            fill_proj(ia, (r2 & 2) ? -1.f : 1.f, par, pai);
            fill_proj(ib, (r2 & 1) ? -1.f : 1.f, pbr, pbi);
        } else if (m < 39) {
            fill_proj(m - 36, 1.f, par, pai);
            fill_id(pbr, pbi);
        } else {
            fill_id(par, pai);
            fill_proj(m - 39, 1.f, pbr, pbi);
        }
        float prob = 0.f;
#pragma unroll
        for (int a1 = 0; a1 < 2; a1++)
#pragma unroll
            for (int b1 = 0; b1 < 2; b1++)
#pragma unroll
                for (int a2 = 0; a2 < 2; a2++)
#pragma unroll
                    for (int b2 = 0; b2 < 2; b2++) {
                        const int i = 2 * a1 + b1, j = 2 * a2 + b2;
                        const float Mr = par[a1][a2] * pbr[b1][b2] - pai[a1][a2] * pbi[b1][b2];
                        const float Mi = par[a1][a2] * pbi[b1][b2] + pai[a1][a2] * pbr[b1][b2];
                        prob += Mr * sr[j * 4 + i] - Mi * si[j * 4 + i];
                    }
        prob = fminf(fmaxf(prob, 0.f), 1.f);
        out[b * 43 + m] = prob;
    } else if (tid == 42) {
        out[b * 43 + 42] = inputs[b];
    }

    if (out_size >= 2752 + 2048) {
        if (tid < 16) {
            out[2752 + b * 32 + 2 * tid]     = sr[tid];
            out[2752 + b * 32 + 2 * tid + 1] = si[tid];
        }
    } else if (out_size >= 2752 + 1024) {
        if (tid < 16) out[2752 + b * 16 + tid] = sr[tid];
    }
}

extern "C" void kernel_launch(void* const* d_in, const int* in_sizes, int n_in,
                              void* d_out, int out_size, void* d_ws, size_t ws_size,
                              hipStream_t stream)
{
    const float* inputs = (const float*)d_in[0];
    const float* params = (const float*)d_in[1];
    const float* wvec   = (const float*)d_in[2];
    const float* rho0   = (const float*)d_in[3];
    const int rho0_cplx = (n_in > 3 && in_sizes[3] >= 32) ? 1 : 0;
    float* ws = (float*)d_ws;

    traj_kernel<<<(NTOT * 16) / 64, 64, 0, stream>>>(inputs, params, wvec, rho0, rho0_cplx, ws);
    reduce_meas_kernel<<<BATCH, 256, 0, stream>>>(ws, inputs, (float*)d_out, out_size);
}

// Round 16
// 32.191 us; speedup vs baseline: 1.2843x; 1.2843x over previous
//
#include <hip/hip_runtime.h>
#include <math.h>

#define BATCH 64
#define NUM_TRAJ 128
#define NTOT (BATCH*NUM_TRAJ)
#define NSTEPS 255

static constexpr float DT = 0.00390625f; // 2^-8

// quad_perm / row DPP shuffle (compile-time ctrl), float
template<int C>
__device__ __forceinline__ float qp(float x) {
    union { float f; int i; } u;
    u.f = x;
    u.i = __builtin_amdgcn_update_dpp(0, u.i, C, 0xF, 0xF, true);
    return u.f;
}
#define DPP_HALF_MIRROR 0x141   // lane -> lane^7 within each 8-lane group

// For the lane holding row r in a quad: sum of the two "other" rows needed by
// H*rho: rows 1+2 for r in {0,3}; rows 0+3 for r in {1,2}. Valid for identity
// and mirrored quads (verified R5/R6).
__device__ __forceinline__ float qsum2(float x) { return qp<65>(x) + qp<190>(x); }

// 8 lanes per trajectory, mirror layout (verified R6/R7/R14): lanes 0-3 =
// (c=0,r=p), lanes 4-7 = (c=1, r=3-p); c=0 owns cols {0,3}, c=1 owns {1,2};
// each element an in-lane (re,im) float pair. Partner at lane^7 (DPP mirror).
// Real-only trace (R14 Hermiticity cut). No LDS-path ops anywhere.
//
// R16 change: the trace reduce for step s+1 is computed IMMEDIATELY after
// step s's update (x = rho(s+1) and dw_{s+1} are both already available) and
// carried in (urc, pownc). This is an exact reordering — same operands, same
// reduce order — that moves the serial tm->3xDPP->ur chain OFF the in-step
// critical path: it now overlaps with the next step's independent u/S/cm
// DPP chains instead of serializing before W.
__global__ __launch_bounds__(64, 1) void traj_kernel(
    const float* __restrict__ inputs,
    const float* __restrict__ params,
    const float* __restrict__ wvec,
    const float* __restrict__ rho0,
    int rho0_cplx,
    float* __restrict__ ws)
{
    const int tid = blockIdx.x * 64 + threadIdx.x;
    const int g  = tid >> 3;          // trajectory index
    const int l8 = tid & 7;           // lane within 8-lane group
    const int p  = l8 & 3;            // position in quad
    const int c  = l8 >> 2;           // column pair: 0->{0,3}, 1->{1,2}
    const int r  = c ? (3 - p) : p;   // row (mirrored in upper quad)
    const int b  = g & (BATCH - 1);

    const float Omega = inputs[b] + 1e-8f;
    const float a     = 0.5f * Omega;
    const float eps   = params[1];
    const float Gamma = params[2];
    const float eta   = params[3];
    const float sqge  = sqrtf(fmaxf(Gamma * eta, 0.0f));
    const float gdt   = Gamma * DT;

    // lane constants
    const float s1   = (r < 2) ? 1.0f : -1.0f;   // C1 diag at row r
    const float s2   = (r & 1) ? -1.0f : 1.0f;   // C2 diag at row r
    const float hr   = (r == 0) ? eps : ((r == 3) ? -eps : 0.0f);
    const int  colA  = c ? 1 : 0;
    const int  colB  = c ? 2 : 3;
    const float s2A  = c ? -1.0f : 1.0f;         // col A signs: s1=+1, s2=s2A
    const float coefA = hr - (c ? 0.0f : eps);   // h_r - h_colA
    const float coefB = hr + (c ? 0.0f : eps);   // h_r - h_colB
    const float dmA  = gdt * ( (s1 + s2 * s2A) - 2.0f);
    const float dmB  = gdt * (-(s1 + s2 * s2A) - 2.0f);
    // sqge folded into the noise-linear constants (raw dw used everywhere):
    const float S1   = s1 * sqge;                // pown = S1*dwA + S2*dwB
    const float S2   = s2 * sqge;
    const float SQ   = sqge;                     // pc = SQ*dwA + PC2*dwB
    const float PC2  = (c ? -1.0f : 1.0f) * sqge;
    // diag ownership: contribute 2*p_r*rho_rr once (tw carries the factor 2).
    const float f1   = (r == colA) ? 1.0f : 0.0f;
    const float f2   = (r == colB) ? 1.0f : 0.0f;

    float qa_re, qa_im, qb_re, qb_im;
    {
        const int idxA = r * 4 + colA, idxB = r * 4 + colB;
        if (rho0_cplx) {
            qa_re = rho0[2 * idxA]; qa_im = rho0[2 * idxA + 1];
            qb_re = rho0[2 * idxB]; qb_im = rho0[2 * idxB + 1];
        } else {
            qa_re = rho0[idxA]; qa_im = 0.0f;
            qb_re = rho0[idxB]; qb_im = 0.0f;
        }
    }

    const float2* wp2 = reinterpret_cast<const float2*>(wvec) + (size_t)g * NSTEPS;

    float urc, pownc;   // carried trace/noise scalars for the UPCOMING step

    // compute (ur, pown) for the step that will consume noise (dwA,dwB),
    // from the CURRENT x (= rho at that step's start). Exact same operand
    // order as R14's in-step version.
    auto calc_next = [&](float dwA, float dwB) {
        const float pown = fmaf(S1, dwA, S2 * dwB);
        const float tw = pown + pown;
        const float tm = tw * fmaf(f1, qa_re, f2 * qb_re);
        float z = tm;
        z += qp<177>(z);              // quad_perm(1,0,3,2)
        z += qp<78>(z);               // quad_perm(2,3,0,1)
        z += qp<DPP_HALF_MIRROR>(z);
        urc = z; pownc = pown;
    };

    auto step = [&](float dwA, float dwB) {
        // rho*H pair sum + partner exchange (lane^7, DPP mirror)
        const float u_re = qa_re + qb_re, u_im = qa_im + qb_im;
        const float up_re = qp<DPP_HALF_MIRROR>(u_re);
        const float up_im = qp<DPP_HALF_MIRROR>(u_im);

        // cross-row sums (quad DPP), per owned column per component
        const float SA_re = qsum2(qa_re), SA_im = qsum2(qa_im);
        const float SB_re = qsum2(qb_re), SB_im = qsum2(qb_im);

        // comm = H rho - rho H; a*up shared across A/B (saves 2 ops)
        const float au_re = a * up_re, au_im = a * up_im;
        const float cA_re = fmaf(coefA, qa_re, fmaf(a, SA_re, -au_re));
        const float cA_im = fmaf(coefA, qa_im, fmaf(a, SA_im, -au_im));
        const float cB_re = fmaf(coefB, qb_re, fmaf(a, SB_re, -au_re));
        const float cB_im = fmaf(coefB, qb_im, fmaf(a, SB_im, -au_im));

        // W from the carried (urc, pownc)
        const float pc   = fmaf(SQ, dwA, PC2 * dwB);
        const float base = pownc - urc;
        const float WA = (base + dmA) + pc;
        const float WB = (base + dmB) - pc;

        // n = x + DT*(c_im,-c_re) + W*x
        float n_re, n_im;
        n_re = fmaf(DT, cA_im, qa_re);  n_re = fmaf(WA, qa_re, n_re);
        n_im = fmaf(-DT, cA_re, qa_im); n_im = fmaf(WA, qa_im, n_im);
        qa_re = n_re; qa_im = n_im;
        n_re = fmaf(DT, cB_im, qb_re);  n_re = fmaf(WB, qb_re, n_re);
        n_im = fmaf(-DT, cB_re, qb_im); n_im = fmaf(WB, qb_im, n_im);
        qb_re = n_re; qb_im = n_im;
    };

    // 31 chunks of 8 steps + tail of 7; group-identical direct loads,
    // double-buffered one chunk ahead. Trace reduce software-pipelined:
    // after each step, immediately compute (urc,pownc) for the next step.
    float2 cw[8], nw[8];
#pragma unroll
    for (int s = 0; s < 8; ++s) cw[s] = wp2[s];
    calc_next(cw[0].x, cw[0].y);
#pragma unroll 1
    for (int T = 0; T < 31; ++T) {
        if (T < 30) {
#pragma unroll
            for (int s = 0; s < 8; ++s) nw[s] = wp2[8 * (T + 1) + s];
        } else {
#pragma unroll
            for (int s = 0; s < 7; ++s) nw[s] = wp2[248 + s];
            nw[7] = make_float2(0.f, 0.f);
        }
#pragma unroll
        for (int s = 0; s < 8; ++s) {
            step(cw[s].x, cw[s].y);
            if (s < 7) calc_next(cw[s + 1].x, cw[s + 1].y);
            else       calc_next(nw[0].x, nw[0].y);
        }
#pragma unroll
        for (int s = 0; s < 8; ++s) cw[s] = nw[s];
    }
    // tail: steps 248..254
#pragma unroll
    for (int s = 0; s < 7; ++s) {
        step(cw[s].x, cw[s].y);
        if (s < 6) calc_next(cw[s + 1].x, cw[s + 1].y);
    }

    // ws per trajectory: slot c*4+r gets float4 (qa_re, qa_im, qb_re, qb_im)
    float4* o = reinterpret_cast<float4*>(ws + (size_t)g * 32);
    o[c * 4 + r] = make_float4(qa_re, qa_im, qb_re, qb_im);
}

__device__ inline void fill_proj(int p, float s, float pr[2][2], float pim[2][2])
{
    pr[0][0] = 0.5f; pr[0][1] = 0.f; pr[1][0] = 0.f; pr[1][1] = 0.5f;
    pim[0][0] = 0.f; pim[0][1] = 0.f; pim[1][0] = 0.f; pim[1][1] = 0.f;
    const float h = 0.5f * s;
    if (p == 0)      { pr[0][1] += h;  pr[1][0] += h; }   // sigma_x
    else if (p == 1) { pim[0][1] -= h; pim[1][0] += h; }  // sigma_y
    else             { pr[0][0] += h;  pr[1][1] -= h; }   // sigma_z
}

__device__ inline void fill_id(float pr[2][2], float pim[2][2])
{
    pr[0][0] = 1.f; pr[0][1] = 0.f; pr[1][0] = 0.f; pr[1][1] = 1.f;
    pim[0][0] = 0.f; pim[0][1] = 0.f; pim[1][0] = 0.f; pim[1][1] = 0.f;
}

// One block per batch element (R7/R14 layout): ws element map for (i,j):
// cc=(j==1||j==2), slot=(j==2||j==3), float index = (cc*4+i)*4 + slot*2 + plane
__global__ __launch_bounds__(256) void reduce_meas_kernel(
    const float* __restrict__ ws,
    const float* __restrict__ inputs,
    float* __restrict__ out,
    int out_size)
{
    const int b = blockIdx.x;
    const int tid = threadIdx.x;
    __shared__ float part[8][32];
    __shared__ float sr[16], si[16];

    {   // 256 threads: element e (32) x k-eighth h (8)
        const int e = tid & 31;
        const int h = tid >> 5;
        const int plane = e >> 4;       // 0 = re, 1 = im
        const int el = e & 15;
        const int i = el >> 2, j = el & 3;
        const int cc = (j == 1 || j == 2) ? 1 : 0;
        const int slot = (j == 2 || j == 3) ? 1 : 0;
        const int fidx = (cc * 4 + i) * 4 + slot * 2 + plane;
        float s = 0.f;
#pragma unroll 4
        for (int k = h * 16; k < h * 16 + 16; k++)
            s += ws[((size_t)(k * BATCH + b)) * 32 + fidx];
        part[h][e] = s;
    }
    __syncthreads();
    if (tid < 32) {
        float s = 0.f;
#pragma unroll
        for (int h = 0; h < 8; h++) s += part[h][tid];
        s *= (1.0f / NUM_TRAJ);
        if (tid < 16) sr[tid] = s; else si[tid - 16] = s;
    }
    __syncthreads();

    if (tid < 42) {
        float par[2][2], pai[2][2], pbr[2][2], pbi[2][2];
        const int m = tid;
        if (m < 36) {
            const int ia = m / 12, rem = m - ia * 12;
            const int ib = rem / 4, r2 = rem - ib * 4;
            fill_proj(ia, (r2 & 2) ? -1.f : 1.f, par, pai);
            fill_proj(ib, (r2 & 1) ? -1.f : 1.f, pbr, pbi);
        } else if (m < 39) {
            fill_proj(m - 36, 1.f, par, pai);
            fill_id(pbr, pbi);
        } else {
            fill_id(par, pai);
            fill_proj(m - 39, 1.f, pbr, pbi);
        }
        float prob = 0.f;
#pragma unroll
        for (int a1 = 0; a1 < 2; a1++)
#pragma unroll
            for (int b1 = 0; b1 < 2; b1++)
#pragma unroll
                for (int a2 = 0; a2 < 2; a2++)
#pragma unroll
                    for (int b2 = 0; b2 < 2; b2++) {
                        const int i = 2 * a1 + b1, j = 2 * a2 + b2;
                        const float Mr = par[a1][a2] * pbr[b1][b2] - pai[a1][a2] * pbi[b1][b2];
                        const float Mi = par[a1][a2] * pbi[b1][b2] + pai[a1][a2] * pbr[b1][b2];
                        prob += Mr * sr[j * 4 + i] - Mi * si[j * 4 + i];
                    }
        prob = fminf(fmaxf(prob, 0.f), 1.f);
        out[b * 43 + m] = prob;
    } else if (tid == 42) {
        out[b * 43 + 42] = inputs[b];
    }

    if (out_size >= 2752 + 2048) {
        if (tid < 16) {
            out[2752 + b * 32 + 2 * tid]     = sr[tid];
            out[2752 + b * 32 + 2 * tid + 1] = si[tid];
        }
    } else if (out_size >= 2752 + 1024) {
        if (tid < 16) out[2752 + b * 16 + tid] = sr[tid];
    }
}

extern "C" void kernel_launch(void* const* d_in, const int* in_sizes, int n_in,
                              void* d_out, int out_size, void* d_ws, size_t ws_size,
                              hipStream_t stream)
{
    const float* inputs = (const float*)d_in[0];
    const float* params = (const float*)d_in[1];
    const float* wvec   = (const float*)d_in[2];
    const float* rho0   = (const float*)d_in[3];
    const int rho0_cplx = (n_in > 3 && in_sizes[3] >= 32) ? 1 : 0;
    float* ws = (float*)d_ws;

    traj_kernel<<<(NTOT * 8) / 64, 64, 0, stream>>>(inputs, params, wvec, rho0, rho0_cplx, ws);
    reduce_meas_kernel<<<BATCH, 256, 0, stream>>>(ws, inputs, (float*)d_out, out_size);
}